// Round 6
// baseline (250.601 us; speedup 1.0000x reference)
//
#include <hip/hip_runtime.h>
#include <hip/hip_bf16.h>

#define N_NODES 500000
#define N_FEAT 125
#define HID 128
#define OUTD 64
#define N_GRAPHS 4096
#define N_TYPES 100
#define WTILE 32
#define NBLOCKS 256
#define NTHREADS 512
#define NWAVES 8
#define WPAD 136    /* bf16 row stride: 16B-aligned; breaks pow2 bank strides */
#define OPADF 68    /* f32 row stride, aliases bf16 scratch exactly */
#define NSLOTS 40   /* per-block graph slots; window ~2100 nodes / min-count ~75 => <=28 used */

typedef float f32x4 __attribute__((ext_vector_type(4)));
typedef short s16x8 __attribute__((ext_vector_type(8)));

// LDS layout (bytes)
#define OFF_W2 0
#define OFF_W3 (OFF_W2 + HID * WPAD * 2)            // 34816
#define OFF_B2 (OFF_W3 + OUTD * WPAD * 2)           // 52224
#define OFF_T  (OFF_B2 + HID * 4)                   // 52736
#define OFF_SCR (OFF_T + N_TYPES * WPAD * 2)        // 79936
#define SCR_BYTES (WTILE * WPAD * 2)                // 8704 per wave
#define OFF_SLOT (OFF_SCR + NWAVES * SCR_BYTES)     // 149568
#define OFF_CNT (OFF_SLOT + NSLOTS * OUTD * 4)      // 159808
#define OFF_IDS (OFF_CNT + NSLOTS * 4)              // 159968
#define LDS_BYTES (OFF_IDS + NWAVES * WTILE * 4)    // 160992 (<= 163840)

__device__ __forceinline__ unsigned short f2bf(float f) {
  union { float f; unsigned u; } v; v.f = f;
  unsigned r = v.u + 0x7FFFu + ((v.u >> 16) & 1u);  // RNE
  return (unsigned short)(r >> 16);
}
__device__ __forceinline__ float bf2f(unsigned short u) {
  union { unsigned u; float f; } v; v.u = ((unsigned)u) << 16;
  return v.f;
}
__device__ __forceinline__ unsigned pk2bf(float a, float b) {
  __hip_bfloat162 h = __float22bfloat162_rn(float2{a, b});   // .x low16, .y high16
  union { __hip_bfloat162 h; unsigned u; } v; v.h = h;
  return v.u;
}

// Wave-local LDS ordering fence (DS pipe is in-order per wave). Proven R3/R4.
__device__ __forceinline__ void wavefence() {
  __builtin_amdgcn_sched_barrier(0);
  __builtin_amdgcn_wave_barrier();
  __builtin_amdgcn_sched_barrier(0);
}

extern "C" __global__ void __launch_bounds__(NTHREADS, 2)
gnn_all(const float* __restrict__ pos, const int* __restrict__ z,
        const int* __restrict__ batch, const float* __restrict__ emb,
        const float* __restrict__ W1, const float* __restrict__ b1,
        const float* __restrict__ W2, const float* __restrict__ b2,
        const float* __restrict__ W3, const float* __restrict__ b3,
        float* __restrict__ out)
{
  extern __shared__ char lds[];
  unsigned short* w2t = (unsigned short*)(lds + OFF_W2);
  unsigned short* w3t = (unsigned short*)(lds + OFF_W3);
  float* bias2 = (float*)(lds + OFF_B2);
  unsigned short* Tl = (unsigned short*)(lds + OFF_T);
  float* slotsum = (float*)(lds + OFF_SLOT);
  int* slotcnt = (int*)(lds + OFF_CNT);

  const int t = threadIdx.x, b = blockIdx.x;
  const int wave = t >> 6, lane = t & 63, quad = lane >> 4, l15 = lane & 15;

  // ---- block's contiguous tile range: 61 tiles (+1 for first 9 blocks) ----
  const int tlo = 61 * b + (b < 9 ? b : 9);
  const int ntl = 61 + (b < 9 ? 1 : 0);
  const int start_node = tlo * WTILE;
  const int end_node = start_node + ntl * WTILE;    // <= N_NODES (15625 tiles exact)

  // ---- stage weights (bf16, [n][k] transposed, padded) ----
  for (int i = t; i < HID * HID; i += NTHREADS) {
    int k = i >> 7, n = i & 127;
    w2t[n * WPAD + k] = f2bf(W2[i]);
  }
  for (int i = t; i < HID * OUTD; i += NTHREADS) {
    int k = i >> 6, n = i & 63;
    w3t[n * WPAD + k] = f2bf(W3[i]);
  }
  if (t < HID) bias2[t] = b2[t];

  // ---- compute T = emb @ W1[3:,:] + b1 per block (~1.4 us, L3-hot inputs) ----
  for (int i = t; i < N_TYPES * (HID / 2); i += NTHREADS) {
    const int g = i >> 6, jp = i & 63, j0 = 2 * jp;  // one type g per wave -> s_loads
    const float* er = emb + g * N_FEAT;
    float2 bb = *(const float2*)&b1[j0];
    float a0 = bb.x, a1 = bb.y;
    for (int k = 0; k < N_FEAT; ++k) {
      float e = er[k];
      float2 w = *(const float2*)&W1[(3 + k) * HID + j0];
      a0 = fmaf(e, w.x, a0); a1 = fmaf(e, w.y, a1);
    }
    *(unsigned*)(Tl + g * WPAD + j0) = pk2bf(a0, a1);
  }

  // ---- zero pooling slots ----
  for (int i = t; i < NSLOTS * OUTD; i += NTHREADS) slotsum[i] = 0.f;
  if (t < NSLOTS) slotcnt[t] = 0;

  // ---- ownership scalars (uniform across block) ----
  const int slot_base = batch[start_node];
  const int prev_g = (b == 0) ? -1 : batch[start_node - 1];
  const int own_hi = batch[end_node - 1];
  int n_ext = 0;
  if (end_node < N_NODES) {
    // extend while next 32-aligned tile still starts inside the owned graph
    while (end_node + WTILE * n_ext < N_NODES &&
           batch[end_node + WTILE * n_ext] == own_hi) ++n_ext;
  }

  // ---- per-lane W1 pos-row coefficients (96 VGPRs) + b3 lane value ----
  float w1r[3][4][8];
  #pragma unroll
  for (int c = 0; c < 3; ++c)
    #pragma unroll
    for (int k = 0; k < 4; ++k)
      #pragma unroll
      for (int j = 0; j < 8; ++j)
        w1r[c][k][j] = W1[c * HID + k * 32 + quad * 8 + j];
  const float b3l = b3[lane];

  unsigned short* xs = (unsigned short*)(lds + OFF_SCR + wave * SCR_BYTES);
  float* xo = (float*)xs;                            // aliases xs (wave-order-safe)
  int* ids = (int*)(lds + OFF_IDS) + wave * WTILE;

  __syncthreads();

  // ================= main loop: waves stride the block's tiles =============
  const int ntot = ntl + n_ext;
  for (int j = wave; j < ntot; j += NWAVES) {
    const int base = start_node + j * WTILE;         // 32-aligned, base+31 < N_NODES

    if (lane < WTILE) ids[lane] = batch[base + lane];

    // layer 1 in VALU, directly into MFMA B-fragments (x^T operand)
    s16x8 a[2][4];
    #pragma unroll
    for (int m = 0; m < 2; ++m) {
      const int node = base + m * 16 + l15;
      const int zi = z[node];
      const float px = pos[node * 3], py = pos[node * 3 + 1], pz = pos[node * 3 + 2];
      const unsigned short* Tr = Tl + zi * WPAD;
      #pragma unroll
      for (int k = 0; k < 4; ++k) {
        s16x8 tf = *(const s16x8*)(Tr + k * 32 + quad * 8);
        s16x8 fr;
        #pragma unroll
        for (int jj = 0; jj < 8; jj += 2) {
          float v0 = bf2f((unsigned short)tf[jj])
                   + px * w1r[0][k][jj] + py * w1r[1][k][jj] + pz * w1r[2][k][jj];
          float v1 = bf2f((unsigned short)tf[jj + 1])
                   + px * w1r[0][k][jj + 1] + py * w1r[1][k][jj + 1] + pz * w1r[2][k][jj + 1];
          ((unsigned*)&fr)[jj >> 1] = pk2bf(fmaxf(v0, 0.f), fmaxf(v1, 0.f));
        }
        a[m][k] = fr;
      }
    }

    // layer 2: D = W2^T(A) x h1^T(B) -> C: row=out-feature, col=node
    f32x4 acc[8][2] = {};
    #pragma unroll
    for (int oi = 0; oi < 8; ++oi)
      #pragma unroll
      for (int k = 0; k < 4; ++k) {
        s16x8 w = *(const s16x8*)(w2t + (oi * 16 + l15) * WPAD + k * 32 + quad * 8);
        acc[oi][0] = __builtin_amdgcn_mfma_f32_16x16x32_bf16(w, a[0][k], acc[oi][0], 0, 0, 0);
        acc[oi][1] = __builtin_amdgcn_mfma_f32_16x16x32_bf16(w, a[1][k], acc[oi][1], 0, 0, 0);
      }
    #pragma unroll
    for (int oi = 0; oi < 8; ++oi) {
      const int f0 = oi * 16 + quad * 4;
      f32x4 bv = *(const f32x4*)(bias2 + f0);
      #pragma unroll
      for (int m = 0; m < 2; ++m) {
        unsigned lo = pk2bf(fmaxf(acc[oi][m][0] + bv[0], 0.f),
                            fmaxf(acc[oi][m][1] + bv[1], 0.f));
        unsigned hi = pk2bf(fmaxf(acc[oi][m][2] + bv[2], 0.f),
                            fmaxf(acc[oi][m][3] + bv[3], 0.f));
        *(uint2*)(xs + (m * 16 + l15) * WPAD + f0) = uint2{lo, hi};
      }
    }
    wavefence();
    #pragma unroll
    for (int m = 0; m < 2; ++m)
      #pragma unroll
      for (int k = 0; k < 4; ++k)
        a[m][k] = *(const s16x8*)(xs + (m * 16 + l15) * WPAD + k * 32 + quad * 8);
    wavefence();

    // layer 3: D = W3^T x h2^T (b3 folded into final write)
    f32x4 acc3[4][2] = {};
    #pragma unroll
    for (int oi = 0; oi < 4; ++oi)
      #pragma unroll
      for (int k = 0; k < 4; ++k) {
        s16x8 w = *(const s16x8*)(w3t + (oi * 16 + l15) * WPAD + k * 32 + quad * 8);
        acc3[oi][0] = __builtin_amdgcn_mfma_f32_16x16x32_bf16(w, a[0][k], acc3[oi][0], 0, 0, 0);
        acc3[oi][1] = __builtin_amdgcn_mfma_f32_16x16x32_bf16(w, a[1][k], acc3[oi][1], 0, 0, 0);
      }
    #pragma unroll
    for (int oi = 0; oi < 4; ++oi)
      #pragma unroll
      for (int m = 0; m < 2; ++m)
        *(f32x4*)(xo + (m * 16 + l15) * OPADF + oi * 16 + quad * 4) = acc3[oi][m];
    wavefence();

    // pool into block-local LDS slots; mask runs not owned by this block
    {
      int cur = ids[0];
      float run = 0.f; int rc = 0;
      #pragma unroll 1
      for (int n = 0; n < WTILE; ++n) {
        int bb2 = ids[n];
        if (bb2 != cur) {
          if (cur != prev_g && cur <= own_hi) {
            atomicAdd(&slotsum[(cur - slot_base) * OUTD + lane], run);
            if (lane == 0) atomicAdd(&slotcnt[cur - slot_base], rc);
          }
          run = 0.f; rc = 0; cur = bb2;
        }
        run += xo[n * OPADF + lane]; rc++;
      }
      if (cur != prev_g && cur <= own_hi) {
        atomicAdd(&slotsum[(cur - slot_base) * OUTD + lane], run);
        if (lane == 0) atomicAdd(&slotcnt[cur - slot_base], rc);
      }
    }
    wavefence();   // next tile reuses xs/ids (same wave)
  }

  __syncthreads();   // all waves' slot contributions visible block-wide

  // ================= final writes: owned graphs + id-gap zero-fill =========
  const int own_lo = slot_base + (slot_base == prev_g ? 1 : 0);
  for (int g = own_lo + wave; g <= own_hi; g += NWAVES) {
    int s = g - slot_base;
    float sum = slotsum[s * OUTD + lane];
    int c = slotcnt[s];
    out[g * OUTD + lane] = (c > 0) ? (sum / (float)c + b3l) : 0.f;
  }
  const int next_g = (end_node < N_NODES) ? batch[end_node] : N_GRAPHS;
  for (int g = own_hi + 1 + wave; g < next_g; g += NWAVES)
    out[g * OUTD + lane] = 0.f;                      // ids with no nodes at boundary
  if (b == 0)
    for (int g = wave; g < slot_base; g += NWAVES)
      out[g * OUTD + lane] = 0.f;                    // leading empty ids
}

extern "C" void kernel_launch(void* const* d_in, const int* in_sizes, int n_in,
                              void* d_out, int out_size, void* d_ws, size_t ws_size,
                              hipStream_t stream) {
  const float* pos  = (const float*)d_in[0];
  const int*   z    = (const int*)d_in[1];
  const int*   batch= (const int*)d_in[2];
  const float* emb  = (const float*)d_in[3];
  const float* W1   = (const float*)d_in[4];
  const float* b1   = (const float*)d_in[5];
  const float* W2   = (const float*)d_in[6];
  const float* b2   = (const float*)d_in[7];
  const float* W3   = (const float*)d_in[8];
  const float* b3   = (const float*)d_in[9];

  hipFuncSetAttribute((const void*)gnn_all,
                      hipFuncAttributeMaxDynamicSharedMemorySize, LDS_BYTES);

  hipLaunchKernelGGL(gnn_all, dim3(NBLOCKS), dim3(NTHREADS), LDS_BYTES, stream,
                     pos, z, batch, emb, W1, b1, W2, b2, W3, b3, (float*)d_out);
}

// Round 7
// 161.322 us; speedup vs baseline: 1.5534x; 1.5534x over previous
//
#include <hip/hip_runtime.h>
#include <hip/hip_bf16.h>

#define N_NODES 500000
#define N_FEAT 125
#define HID 128
#define OUTD 64
#define N_GRAPHS 4096
#define N_TYPES 100
#define WTILE 32
#define NBLOCKS 256
#define NTHREADS 512
#define NWAVES 8
#define WPAD 136    /* bf16 row stride: 16B-aligned; breaks pow2 bank strides */
#define OPADF 68    /* f32 row stride, aliases bf16 scratch exactly */
#define NSLOTS 40   /* per-block graph slots; window ~2100 nodes => <=~20 used */

typedef float f32x4 __attribute__((ext_vector_type(4)));
typedef short s16x8 __attribute__((ext_vector_type(8)));

// LDS layout (bytes)
#define OFF_W2 0
#define OFF_W3 (OFF_W2 + HID * WPAD * 2)            // 34816
#define OFF_B2 (OFF_W3 + OUTD * WPAD * 2)           // 52224
#define OFF_T  (OFF_B2 + HID * 4)                   // 52736
#define OFF_SCR (OFF_T + N_TYPES * WPAD * 2)        // 79936
#define SCR_BYTES (WTILE * WPAD * 2)                // 8704 per wave
#define OFF_SLOT (OFF_SCR + NWAVES * SCR_BYTES)     // 149568
#define OFF_CNT (OFF_SLOT + NSLOTS * OUTD * 4)      // 159808
#define OFF_IDS (OFF_CNT + NSLOTS * 4)              // 159968
#define LDS_BYTES (OFF_IDS + NWAVES * WTILE * 4)    // 160992 (<= 163840)
// During init, the SCR region (69632 B) temporarily holds W1[3:]^T bf16
// (HID*WPAD*2 = 34816 B) for the MFMA T-compute; freed before main loop.

__device__ __forceinline__ unsigned short f2bf(float f) {
  union { float f; unsigned u; } v; v.f = f;
  unsigned r = v.u + 0x7FFFu + ((v.u >> 16) & 1u);  // RNE
  return (unsigned short)(r >> 16);
}
__device__ __forceinline__ float bf2f(unsigned short u) {
  union { unsigned u; float f; } v; v.u = ((unsigned)u) << 16;
  return v.f;
}
__device__ __forceinline__ unsigned pk2bf(float a, float b) {
  __hip_bfloat162 h = __float22bfloat162_rn(float2{a, b});   // .x low16, .y high16
  union { __hip_bfloat162 h; unsigned u; } v; v.h = h;
  return v.u;
}

// Wave-local LDS ordering fence (DS pipe is in-order per wave). Proven R3/R4.
__device__ __forceinline__ void wavefence() {
  __builtin_amdgcn_sched_barrier(0);
  __builtin_amdgcn_wave_barrier();
  __builtin_amdgcn_sched_barrier(0);
}

extern "C" __global__ void __launch_bounds__(NTHREADS, 2)
gnn_all(const float* __restrict__ pos, const int* __restrict__ z,
        const int* __restrict__ batch, const float* __restrict__ emb,
        const float* __restrict__ W1, const float* __restrict__ b1,
        const float* __restrict__ W2, const float* __restrict__ b2,
        const float* __restrict__ W3, const float* __restrict__ b3,
        float* __restrict__ out)
{
  extern __shared__ char lds[];
  unsigned short* w2t = (unsigned short*)(lds + OFF_W2);
  unsigned short* w3t = (unsigned short*)(lds + OFF_W3);
  float* bias2 = (float*)(lds + OFF_B2);
  unsigned short* Tl = (unsigned short*)(lds + OFF_T);
  unsigned short* w1t = (unsigned short*)(lds + OFF_SCR);   // init-phase only
  float* slotsum = (float*)(lds + OFF_SLOT);
  int* slotcnt = (int*)(lds + OFF_CNT);

  const int t = threadIdx.x, b = blockIdx.x;
  const int wave = t >> 6, lane = t & 63, quad = lane >> 4, l15 = lane & 15;

  // ---- block's contiguous tile range: 61 tiles (+1 for first 9 blocks) ----
  const int tlo = 61 * b + (b < 9 ? b : 9);
  const int ntl = 61 + (b < 9 ? 1 : 0);
  const int start_node = tlo * WTILE;
  const int end_node = start_node + ntl * WTILE;    // <= N_NODES (15625 tiles exact)

  // ---- stage weights (bf16, [n][k] transposed, padded) ----
  for (int i = t; i < HID * HID; i += NTHREADS) {
    int k = i >> 7, n = i & 127;
    w2t[n * WPAD + k] = f2bf(W2[i]);
  }
  for (int i = t; i < HID * OUTD; i += NTHREADS) {
    int k = i >> 6, n = i & 63;
    w3t[n * WPAD + k] = f2bf(W3[i]);
  }
  // W1[3:]^T bf16 into scratch region: [j][k], zero-padded k=125..127
  for (int i = t; i < HID * HID; i += NTHREADS) {
    int k = i >> 7, j = i & 127;
    w1t[j * WPAD + k] = (k < N_FEAT) ? f2bf(W1[(3 + k) * HID + j]) : (unsigned short)0;
  }
  if (t < HID) bias2[t] = b2[t];

  // ---- zero pooling slots ----
  for (int i = t; i < NSLOTS * OUTD; i += NTHREADS) slotsum[i] = 0.f;
  if (t < NSLOTS) slotcnt[t] = 0;

  // ---- ownership scalars (uniform across block) ----
  const int slot_base = batch[start_node];
  const int prev_g = (b == 0) ? -1 : batch[start_node - 1];
  const int own_hi = batch[end_node - 1];
  int n_ext = 0;
  if (end_node < N_NODES) {
    while (end_node + WTILE * n_ext < N_NODES &&
           batch[end_node + WTILE * n_ext] == own_hi) ++n_ext;
  }

  // ---- per-lane W1 pos-row coefficients (96 VGPRs) + b3 lane value ----
  float w1r[3][4][8];
  #pragma unroll
  for (int c = 0; c < 3; ++c)
    #pragma unroll
    for (int k = 0; k < 4; ++k)
      #pragma unroll
      for (int j = 0; j < 8; ++j)
        w1r[c][k][j] = W1[c * HID + k * 32 + quad * 8 + j];
  const float b3l = b3[lane];

  __syncthreads();   // w1t/w2t/w3t staged

  // ======== T = emb @ W1[3:] + b1 via MFMA (wave jt = wave's j-tile) ========
  {
    const int jt = wave;                              // 8 waves <-> 8 j-tiles of 16
    s16x8 afr[4];
    #pragma unroll
    for (int kf = 0; kf < 4; ++kf)
      afr[kf] = *(const s16x8*)(w1t + (jt * 16 + l15) * WPAD + kf * 32 + quad * 8);

    const int j0 = jt * 16 + quad * 4;
    const f32x4 b1v = *(const f32x4*)&b1[j0];

    for (int gt = 0; gt < 7; ++gt) {                  // 7 g-tiles of 16 (100 -> 112)
      const int g = gt * 16 + l15;
      const int gg = (g < N_TYPES) ? g : (N_TYPES - 1);   // clamp: avoid OOB read
      const float* erow = emb + gg * N_FEAT;
      f32x4 acc = {};
      #pragma unroll
      for (int kf = 0; kf < 4; ++kf) {
        s16x8 bf;
        #pragma unroll
        for (int u = 0; u < 8; ++u) {
          const int k = kf * 32 + quad * 8 + u;
          float v = (k < N_FEAT) ? erow[k] : 0.f;     // k-tail masked
          bf[u] = (short)f2bf(v);
        }
        acc = __builtin_amdgcn_mfma_f32_16x16x32_bf16(afr[kf], bf, acc, 0, 0, 0);
      }
      // D: row m = quad*4+r (j-sub), col n = l15 (g). Store 4 consecutive j.
      if (g < N_TYPES) {
        unsigned lo = pk2bf(acc[0] + b1v[0], acc[1] + b1v[1]);
        unsigned hi = pk2bf(acc[2] + b1v[2], acc[3] + b1v[3]);
        *(uint2*)(Tl + g * WPAD + j0) = uint2{lo, hi};
      }
    }
  }

  unsigned short* xs = (unsigned short*)(lds + OFF_SCR + wave * SCR_BYTES);
  float* xo = (float*)xs;                            // aliases xs (wave-order-safe)
  int* ids = (int*)(lds + OFF_IDS) + wave * WTILE;

  __syncthreads();   // Tl complete; w1t region now free -> per-wave scratch

  // ================= main loop: waves stride the block's tiles =============
  const int ntot = ntl + n_ext;
  for (int j = wave; j < ntot; j += NWAVES) {
    const int base = start_node + j * WTILE;         // 32-aligned, base+31 < N_NODES

    if (lane < WTILE) ids[lane] = batch[base + lane];

    // layer 1 in VALU, directly into MFMA B-fragments (x^T operand)
    s16x8 a[2][4];
    #pragma unroll
    for (int m = 0; m < 2; ++m) {
      const int node = base + m * 16 + l15;
      const int zi = z[node];
      const float px = pos[node * 3], py = pos[node * 3 + 1], pz = pos[node * 3 + 2];
      const unsigned short* Tr = Tl + zi * WPAD;
      #pragma unroll
      for (int k = 0; k < 4; ++k) {
        s16x8 tf = *(const s16x8*)(Tr + k * 32 + quad * 8);
        s16x8 fr;
        #pragma unroll
        for (int jj = 0; jj < 8; jj += 2) {
          float v0 = bf2f((unsigned short)tf[jj])
                   + px * w1r[0][k][jj] + py * w1r[1][k][jj] + pz * w1r[2][k][jj];
          float v1 = bf2f((unsigned short)tf[jj + 1])
                   + px * w1r[0][k][jj + 1] + py * w1r[1][k][jj + 1] + pz * w1r[2][k][jj + 1];
          ((unsigned*)&fr)[jj >> 1] = pk2bf(fmaxf(v0, 0.f), fmaxf(v1, 0.f));
        }
        a[m][k] = fr;
      }
    }

    // layer 2: D = W2^T(A) x h1^T(B) -> C: row=out-feature, col=node
    f32x4 acc[8][2] = {};
    #pragma unroll
    for (int oi = 0; oi < 8; ++oi)
      #pragma unroll
      for (int k = 0; k < 4; ++k) {
        s16x8 w = *(const s16x8*)(w2t + (oi * 16 + l15) * WPAD + k * 32 + quad * 8);
        acc[oi][0] = __builtin_amdgcn_mfma_f32_16x16x32_bf16(w, a[0][k], acc[oi][0], 0, 0, 0);
        acc[oi][1] = __builtin_amdgcn_mfma_f32_16x16x32_bf16(w, a[1][k], acc[oi][1], 0, 0, 0);
      }
    #pragma unroll
    for (int oi = 0; oi < 8; ++oi) {
      const int f0 = oi * 16 + quad * 4;
      f32x4 bv = *(const f32x4*)(bias2 + f0);
      #pragma unroll
      for (int m = 0; m < 2; ++m) {
        unsigned lo = pk2bf(fmaxf(acc[oi][m][0] + bv[0], 0.f),
                            fmaxf(acc[oi][m][1] + bv[1], 0.f));
        unsigned hi = pk2bf(fmaxf(acc[oi][m][2] + bv[2], 0.f),
                            fmaxf(acc[oi][m][3] + bv[3], 0.f));
        *(uint2*)(xs + (m * 16 + l15) * WPAD + f0) = uint2{lo, hi};
      }
    }
    wavefence();
    #pragma unroll
    for (int m = 0; m < 2; ++m)
      #pragma unroll
      for (int k = 0; k < 4; ++k)
        a[m][k] = *(const s16x8*)(xs + (m * 16 + l15) * WPAD + k * 32 + quad * 8);
    wavefence();

    // layer 3: D = W3^T x h2^T (b3 folded into final write)
    f32x4 acc3[4][2] = {};
    #pragma unroll
    for (int oi = 0; oi < 4; ++oi)
      #pragma unroll
      for (int k = 0; k < 4; ++k) {
        s16x8 w = *(const s16x8*)(w3t + (oi * 16 + l15) * WPAD + k * 32 + quad * 8);
        acc3[oi][0] = __builtin_amdgcn_mfma_f32_16x16x32_bf16(w, a[0][k], acc3[oi][0], 0, 0, 0);
        acc3[oi][1] = __builtin_amdgcn_mfma_f32_16x16x32_bf16(w, a[1][k], acc3[oi][1], 0, 0, 0);
      }
    #pragma unroll
    for (int oi = 0; oi < 4; ++oi)
      #pragma unroll
      for (int m = 0; m < 2; ++m)
        *(f32x4*)(xo + (m * 16 + l15) * OPADF + oi * 16 + quad * 4) = acc3[oi][m];
    wavefence();

    // pool into block-local LDS slots; mask runs not owned by this block
    {
      int cur = ids[0];
      float run = 0.f; int rc = 0;
      #pragma unroll 1
      for (int n = 0; n < WTILE; ++n) {
        int bb2 = ids[n];
        if (bb2 != cur) {
          if (cur != prev_g && cur <= own_hi) {
            atomicAdd(&slotsum[(cur - slot_base) * OUTD + lane], run);
            if (lane == 0) atomicAdd(&slotcnt[cur - slot_base], rc);
          }
          run = 0.f; rc = 0; cur = bb2;
        }
        run += xo[n * OPADF + lane]; rc++;
      }
      if (cur != prev_g && cur <= own_hi) {
        atomicAdd(&slotsum[(cur - slot_base) * OUTD + lane], run);
        if (lane == 0) atomicAdd(&slotcnt[cur - slot_base], rc);
      }
    }
    wavefence();   // next tile reuses xs/ids (same wave)
  }

  __syncthreads();   // all waves' slot contributions visible block-wide

  // ================= final writes: owned graphs + id-gap zero-fill =========
  const int own_lo = slot_base + (slot_base == prev_g ? 1 : 0);
  for (int g = own_lo + wave; g <= own_hi; g += NWAVES) {
    int s = g - slot_base;
    float sum = slotsum[s * OUTD + lane];
    int c = slotcnt[s];
    out[g * OUTD + lane] = (c > 0) ? (sum / (float)c + b3l) : 0.f;
  }
  const int next_g = (end_node < N_NODES) ? batch[end_node] : N_GRAPHS;
  for (int g = own_hi + 1 + wave; g < next_g; g += NWAVES)
    out[g * OUTD + lane] = 0.f;                      // ids with no nodes at boundary
  if (b == 0)
    for (int g = wave; g < slot_base; g += NWAVES)
      out[g * OUTD + lane] = 0.f;                    // leading empty ids
}

extern "C" void kernel_launch(void* const* d_in, const int* in_sizes, int n_in,
                              void* d_out, int out_size, void* d_ws, size_t ws_size,
                              hipStream_t stream) {
  const float* pos  = (const float*)d_in[0];
  const int*   z    = (const int*)d_in[1];
  const int*   batch= (const int*)d_in[2];
  const float* emb  = (const float*)d_in[3];
  const float* W1   = (const float*)d_in[4];
  const float* b1   = (const float*)d_in[5];
  const float* W2   = (const float*)d_in[6];
  const float* b2   = (const float*)d_in[7];
  const float* W3   = (const float*)d_in[8];
  const float* b3   = (const float*)d_in[9];

  hipFuncSetAttribute((const void*)gnn_all,
                      hipFuncAttributeMaxDynamicSharedMemorySize, LDS_BYTES);

  hipLaunchKernelGGL(gnn_all, dim3(NBLOCKS), dim3(NTHREADS), LDS_BYTES, stream,
                     pos, z, batch, emb, W1, b1, W2, b2, W3, b3, (float*)d_out);
}

// Round 8
// 151.081 us; speedup vs baseline: 1.6587x; 1.0678x over previous
//
#include <hip/hip_runtime.h>
#include <hip/hip_bf16.h>

#define N_NODES 500000
#define N_FEAT 125
#define HID 128
#define OUTD 64
#define N_GRAPHS 4096
#define N_TYPES 100
#define WTILE 32
#define NBLOCKS 256
#define NTHREADS 512
#define NWAVES 8
#define WPAD 136    /* bf16 row stride: 16B-aligned; breaks pow2 bank strides */
#define OPADF 68    /* f32 row stride, aliases bf16 scratch exactly */
#define NSLOTS 40   /* per-block graph slots; window ~2100 nodes => <=~20 used */
#define EPAD 132    /* f32 emb row stride during init: 16B-aligned, bank-varying */

typedef float f32x4 __attribute__((ext_vector_type(4)));
typedef float f32x2 __attribute__((ext_vector_type(2)));
typedef short s16x8 __attribute__((ext_vector_type(8)));

// LDS layout (bytes)
#define OFF_W2 0
#define OFF_W3 (OFF_W2 + HID * WPAD * 2)            // 34816
#define OFF_B2 (OFF_W3 + OUTD * WPAD * 2)           // 52224
#define OFF_T  (OFF_B2 + HID * 4)                   // 52736
#define OFF_SCR (OFF_T + N_TYPES * WPAD * 2)        // 79936
#define SCR_BYTES (WTILE * WPAD * 2)                // 8704 per wave
#define OFF_SLOT (OFF_SCR + NWAVES * SCR_BYTES)     // 149568
#define OFF_CNT (OFF_SLOT + NSLOTS * OUTD * 4)      // 159808
#define OFF_IDS (OFF_CNT + NSLOTS * 4)              // 159968
#define LDS_BYTES (OFF_IDS + NWAVES * WTILE * 4)    // 160992 (<= 163840)
// During init, the SCR region (69632 B) temporarily holds emb as f32
// [N_TYPES][EPAD] = 52800 B for the MFMA T-compute; freed before main loop.

__device__ __forceinline__ unsigned short f2bf(float f) {
  union { float f; unsigned u; } v; v.f = f;
  unsigned r = v.u + 0x7FFFu + ((v.u >> 16) & 1u);  // RNE
  return (unsigned short)(r >> 16);
}
__device__ __forceinline__ unsigned pk2bf(float a, float b) {
  __hip_bfloat162 h = __float22bfloat162_rn(float2{a, b});   // .x low16, .y high16
  union { __hip_bfloat162 h; unsigned u; } v; v.h = h;
  return v.u;
}
__device__ __forceinline__ f32x2 unpk_bf2(unsigned u) {
  union { unsigned u; float f; } lo, hi;
  lo.u = u << 16; hi.u = u & 0xffff0000u;
  return (f32x2){lo.f, hi.f};
}

// Wave-local LDS ordering fence (DS pipe is in-order per wave). Proven R3/R4.
__device__ __forceinline__ void wavefence() {
  __builtin_amdgcn_sched_barrier(0);
  __builtin_amdgcn_wave_barrier();
  __builtin_amdgcn_sched_barrier(0);
}

extern "C" __global__ void __launch_bounds__(NTHREADS, 2)
gnn_all(const float* __restrict__ pos, const int* __restrict__ z,
        const int* __restrict__ batch, const float* __restrict__ emb,
        const float* __restrict__ W1, const float* __restrict__ b1,
        const float* __restrict__ W2, const float* __restrict__ b2,
        const float* __restrict__ W3, const float* __restrict__ b3,
        float* __restrict__ out)
{
  extern __shared__ char lds[];
  unsigned short* w2t = (unsigned short*)(lds + OFF_W2);
  unsigned short* w3t = (unsigned short*)(lds + OFF_W3);
  float* bias2 = (float*)(lds + OFF_B2);
  unsigned short* Tl = (unsigned short*)(lds + OFF_T);
  float* embs = (float*)(lds + OFF_SCR);            // init-phase only
  float* slotsum = (float*)(lds + OFF_SLOT);
  int* slotcnt = (int*)(lds + OFF_CNT);

  const int t = threadIdx.x, b = blockIdx.x;
  const int wave = t >> 6, lane = t & 63, quad = lane >> 4, l15 = lane & 15;

  // ---- block's contiguous tile range: 61 tiles (+1 for first 9 blocks) ----
  const int tlo = 61 * b + (b < 9 ? b : 9);
  const int ntl = 61 + (b < 9 ? 1 : 0);
  const int start_node = tlo * WTILE;
  const int end_node = start_node + ntl * WTILE;    // <= N_NODES (15625 tiles exact)

  // ---- stage weights (bf16, [n][k] transposed, padded) ----
  for (int i = t; i < HID * HID; i += NTHREADS) {
    int k = i >> 7, n = i & 127;
    w2t[n * WPAD + k] = f2bf(W2[i]);
  }
  for (int i = t; i < HID * OUTD; i += NTHREADS) {
    int k = i >> 6, n = i & 63;
    w3t[n * WPAD + k] = f2bf(W3[i]);
  }
  // emb as f32 into scratch: [g][k], k zero-padded 125..131 (coalesced reads)
  for (int i = t; i < N_TYPES * EPAD; i += NTHREADS) {
    int g = i / EPAD, k = i - g * EPAD;
    embs[i] = (k < N_FEAT) ? emb[g * N_FEAT + k] : 0.f;
  }
  if (t < HID) bias2[t] = b2[t];

  // ---- zero pooling slots ----
  for (int i = t; i < NSLOTS * OUTD; i += NTHREADS) slotsum[i] = 0.f;
  if (t < NSLOTS) slotcnt[t] = 0;

  // ---- ownership scalars (uniform across block) ----
  const int slot_base = batch[start_node];
  const int prev_g = (b == 0) ? -1 : batch[start_node - 1];
  const int own_hi = batch[end_node - 1];
  int n_ext = 0;
  if (end_node < N_NODES) {
    // parallel probe: 12 lanes test the next 12 tile-starts at once
    int probe = -1;
    if (lane < 12 && end_node + lane * WTILE < N_NODES)
      probe = batch[end_node + lane * WTILE];
    unsigned long long m = __ballot(probe == own_hi);
    n_ext = (int)__builtin_ctzll(~m);                // run of leading matches
    if (n_ext == 12) {                                // ~impossible; stay correct
      while (end_node + WTILE * n_ext < N_NODES &&
             batch[end_node + WTILE * n_ext] == own_hi) ++n_ext;
    }
  }

  // ---- per-lane W1 pos-row coefficients as f32x2 pairs + b3 lane value ----
  f32x2 w1r2[3][4][4];
  #pragma unroll
  for (int c = 0; c < 3; ++c)
    #pragma unroll
    for (int k = 0; k < 4; ++k)
      #pragma unroll
      for (int p = 0; p < 4; ++p)
        w1r2[c][k][p] = *(const f32x2*)&W1[c * HID + k * 32 + quad * 8 + 2 * p];
  const float b3l = b3[lane];

  // ---- T-compute A-frags: W1[3:]^T bf16 straight from global (once) ----
  s16x8 afr[4];
  {
    const int jt = wave;
    #pragma unroll
    for (int kf = 0; kf < 4; ++kf) {
      s16x8 fr;
      #pragma unroll
      for (int u = 0; u < 8; ++u) {
        const int k = kf * 32 + quad * 8 + u;
        float v = (k < N_FEAT) ? W1[(3 + k) * HID + jt * 16 + l15] : 0.f;
        fr[u] = (short)f2bf(v);
      }
      afr[kf] = fr;
    }
  }

  __syncthreads();   // embs/w2t/w3t staged

  // ======== T = emb @ W1[3:] + b1 via MFMA (wave jt = wave's j-tile) ========
  {
    const int jt = wave;                              // 8 waves <-> 8 j-tiles of 16
    const int j0 = jt * 16 + quad * 4;
    const f32x4 b1v = *(const f32x4*)&b1[j0];

    for (int gt = 0; gt < 7; ++gt) {                  // 7 g-tiles of 16 (100 -> 112)
      const int g = gt * 16 + l15;
      const int gg = (g < N_TYPES) ? g : (N_TYPES - 1);   // clamp (pad rows unused)
      const float* erow = embs + gg * EPAD;
      f32x4 acc = {};
      #pragma unroll
      for (int kf = 0; kf < 4; ++kf) {
        const int k0 = kf * 32 + quad * 8;
        f32x4 e0 = *(const f32x4*)(erow + k0);        // zero-padded k>=125
        f32x4 e1 = *(const f32x4*)(erow + k0 + 4);
        s16x8 bf;
        ((unsigned*)&bf)[0] = pk2bf(e0[0], e0[1]);
        ((unsigned*)&bf)[1] = pk2bf(e0[2], e0[3]);
        ((unsigned*)&bf)[2] = pk2bf(e1[0], e1[1]);
        ((unsigned*)&bf)[3] = pk2bf(e1[2], e1[3]);
        acc = __builtin_amdgcn_mfma_f32_16x16x32_bf16(afr[kf], bf, acc, 0, 0, 0);
      }
      if (g < N_TYPES) {                              // D: row=j-sub, col=g
        unsigned lo = pk2bf(acc[0] + b1v[0], acc[1] + b1v[1]);
        unsigned hi = pk2bf(acc[2] + b1v[2], acc[3] + b1v[3]);
        *(uint2*)(Tl + g * WPAD + j0) = uint2{lo, hi};
      }
    }
  }

  unsigned short* xs = (unsigned short*)(lds + OFF_SCR + wave * SCR_BYTES);
  float* xo = (float*)xs;                            // aliases xs (wave-order-safe)
  int* ids = (int*)(lds + OFF_IDS) + wave * WTILE;

  __syncthreads();   // Tl complete; embs region now free -> per-wave scratch

  // ================= main loop: waves stride the block's tiles =============
  const int ntot = ntl + n_ext;
  for (int j = wave; j < ntot; j += NWAVES) {
    const int base = start_node + j * WTILE;         // 32-aligned, base+31 < N_NODES

    if (lane < WTILE) ids[lane] = batch[base + lane];

    // layer 1 in packed VALU, directly into MFMA B-fragments (x^T operand)
    s16x8 a[2][4];
    #pragma unroll
    for (int m = 0; m < 2; ++m) {
      const int node = base + m * 16 + l15;
      const int zi = z[node];
      const f32x2 px2 = {pos[node * 3], pos[node * 3]};
      const f32x2 py2 = {pos[node * 3 + 1], pos[node * 3 + 1]};
      const f32x2 pz2 = {pos[node * 3 + 2], pos[node * 3 + 2]};
      const unsigned short* Tr = Tl + zi * WPAD;
      #pragma unroll
      for (int k = 0; k < 4; ++k) {
        s16x8 tf = *(const s16x8*)(Tr + k * 32 + quad * 8);
        s16x8 fr;
        #pragma unroll
        for (int p = 0; p < 4; ++p) {
          f32x2 tv = unpk_bf2(((const unsigned*)&tf)[p]);
          tv = __builtin_elementwise_fma(px2, w1r2[0][k][p], tv);
          tv = __builtin_elementwise_fma(py2, w1r2[1][k][p], tv);
          tv = __builtin_elementwise_fma(pz2, w1r2[2][k][p], tv);
          tv = __builtin_elementwise_max(tv, (f32x2){0.f, 0.f});
          ((unsigned*)&fr)[p] = pk2bf(tv[0], tv[1]);
        }
        a[m][k] = fr;
      }
    }

    // layer 2: D = W2^T(A) x h1^T(B) -> C: row=out-feature, col=node
    f32x4 acc[8][2] = {};
    #pragma unroll
    for (int oi = 0; oi < 8; ++oi)
      #pragma unroll
      for (int k = 0; k < 4; ++k) {
        s16x8 w = *(const s16x8*)(w2t + (oi * 16 + l15) * WPAD + k * 32 + quad * 8);
        acc[oi][0] = __builtin_amdgcn_mfma_f32_16x16x32_bf16(w, a[0][k], acc[oi][0], 0, 0, 0);
        acc[oi][1] = __builtin_amdgcn_mfma_f32_16x16x32_bf16(w, a[1][k], acc[oi][1], 0, 0, 0);
      }
    #pragma unroll
    for (int oi = 0; oi < 8; ++oi) {
      const int f0 = oi * 16 + quad * 4;
      f32x4 bv = *(const f32x4*)(bias2 + f0);
      #pragma unroll
      for (int m = 0; m < 2; ++m) {
        f32x4 s = acc[oi][m] + bv;                   // v_pk_add_f32 x2
        s = __builtin_elementwise_max(s, (f32x4){0.f, 0.f, 0.f, 0.f});
        unsigned lo = pk2bf(s[0], s[1]);
        unsigned hi = pk2bf(s[2], s[3]);
        *(uint2*)(xs + (m * 16 + l15) * WPAD + f0) = uint2{lo, hi};
      }
    }
    wavefence();
    #pragma unroll
    for (int m = 0; m < 2; ++m)
      #pragma unroll
      for (int k = 0; k < 4; ++k)
        a[m][k] = *(const s16x8*)(xs + (m * 16 + l15) * WPAD + k * 32 + quad * 8);
    wavefence();

    // layer 3: D = W3^T x h2^T (b3 folded into final write)
    f32x4 acc3[4][2] = {};
    #pragma unroll
    for (int oi = 0; oi < 4; ++oi)
      #pragma unroll
      for (int k = 0; k < 4; ++k) {
        s16x8 w = *(const s16x8*)(w3t + (oi * 16 + l15) * WPAD + k * 32 + quad * 8);
        acc3[oi][0] = __builtin_amdgcn_mfma_f32_16x16x32_bf16(w, a[0][k], acc3[oi][0], 0, 0, 0);
        acc3[oi][1] = __builtin_amdgcn_mfma_f32_16x16x32_bf16(w, a[1][k], acc3[oi][1], 0, 0, 0);
      }
    #pragma unroll
    for (int oi = 0; oi < 4; ++oi)
      #pragma unroll
      for (int m = 0; m < 2; ++m)
        *(f32x4*)(xo + (m * 16 + l15) * OPADF + oi * 16 + quad * 4) = acc3[oi][m];
    wavefence();

    // pool into block-local LDS slots; mask runs not owned by this block
    {
      int cur = ids[0];
      float run = 0.f; int rc = 0;
      #pragma unroll 1
      for (int n = 0; n < WTILE; ++n) {
        int bb2 = ids[n];
        if (bb2 != cur) {
          if (cur != prev_g && cur <= own_hi) {
            atomicAdd(&slotsum[(cur - slot_base) * OUTD + lane], run);
            if (lane == 0) atomicAdd(&slotcnt[cur - slot_base], rc);
          }
          run = 0.f; rc = 0; cur = bb2;
        }
        run += xo[n * OPADF + lane]; rc++;
      }
      if (cur != prev_g && cur <= own_hi) {
        atomicAdd(&slotsum[(cur - slot_base) * OUTD + lane], run);
        if (lane == 0) atomicAdd(&slotcnt[cur - slot_base], rc);
      }
    }
    wavefence();   // next tile reuses xs/ids (same wave)
  }

  __syncthreads();   // all waves' slot contributions visible block-wide

  // ================= final writes: owned graphs + id-gap zero-fill =========
  const int own_lo = slot_base + (slot_base == prev_g ? 1 : 0);
  for (int g = own_lo + wave; g <= own_hi; g += NWAVES) {
    int s = g - slot_base;
    float sum = slotsum[s * OUTD + lane];
    int c = slotcnt[s];
    out[g * OUTD + lane] = (c > 0) ? (sum / (float)c + b3l) : 0.f;
  }
  const int next_g = (end_node < N_NODES) ? batch[end_node] : N_GRAPHS;
  for (int g = own_hi + 1 + wave; g < next_g; g += NWAVES)
    out[g * OUTD + lane] = 0.f;                      // ids with no nodes at boundary
  if (b == 0)
    for (int g = wave; g < slot_base; g += NWAVES)
      out[g * OUTD + lane] = 0.f;                    // leading empty ids
}

extern "C" void kernel_launch(void* const* d_in, const int* in_sizes, int n_in,
                              void* d_out, int out_size, void* d_ws, size_t ws_size,
                              hipStream_t stream) {
  const float* pos  = (const float*)d_in[0];
  const int*   z    = (const int*)d_in[1];
  const int*   batch= (const int*)d_in[2];
  const float* emb  = (const float*)d_in[3];
  const float* W1   = (const float*)d_in[4];
  const float* b1   = (const float*)d_in[5];
  const float* W2   = (const float*)d_in[6];
  const float* b2   = (const float*)d_in[7];
  const float* W3   = (const float*)d_in[8];
  const float* b3   = (const float*)d_in[9];

  hipFuncSetAttribute((const void*)gnn_all,
                      hipFuncAttributeMaxDynamicSharedMemorySize, LDS_BYTES);

  hipLaunchKernelGGL(gnn_all, dim3(NBLOCKS), dim3(NTHREADS), LDS_BYTES, stream,
                     pos, z, batch, emb, W1, b1, W2, b2, W3, b3, (float*)d_out);
}

// Round 9
// 150.674 us; speedup vs baseline: 1.6632x; 1.0027x over previous
//
#include <hip/hip_runtime.h>
#include <hip/hip_bf16.h>

#define N_NODES 500000
#define N_FEAT 125
#define HID 128
#define OUTD 64
#define N_GRAPHS 4096
#define N_TYPES 100
#define WTILE 32
#define NBLOCKS 256
#define NTHREADS 512
#define NWAVES 8
#define WPAD 136    /* bf16 row stride: 16B-aligned; breaks pow2 bank strides */
#define OPADF 68    /* f32 row stride for pooling buffer */
#define NSLOTS 40   /* per-block graph slots; window ~2100 nodes => <=~20 used */
#define EPAD 132    /* f32 emb row stride during init: 16B-aligned, bank-varying */

typedef float f32x4 __attribute__((ext_vector_type(4)));
typedef float f32x2 __attribute__((ext_vector_type(2)));
typedef short s16x8 __attribute__((ext_vector_type(8)));

// LDS layout (bytes)
#define OFF_W2 0
#define OFF_W3 (OFF_W2 + HID * WPAD * 2)            // 34816
#define OFF_B2 (OFF_W3 + OUTD * WPAD * 2)           // 52224
#define OFF_T  (OFF_B2 + HID * 4)                   // 52736
#define OFF_SCR (OFF_T + N_TYPES * WPAD * 2)        // 79936
#define SCR_BYTES (WTILE * OPADF * 4)               // 8704 per wave (f32 pool buf)
#define OFF_SLOT (OFF_SCR + NWAVES * SCR_BYTES)     // 149568
#define OFF_CNT (OFF_SLOT + NSLOTS * OUTD * 4)      // 159808
#define OFF_IDS (OFF_CNT + NSLOTS * 4)              // 159968
#define LDS_BYTES (OFF_IDS + NWAVES * WTILE * 4)    // 160992 (<= 163840)
// During init, the SCR region temporarily holds emb as f32 [N_TYPES][EPAD]
// (52800 B) for the MFMA T-compute; freed before the main loop.

// Feature permutation: MFMA-row rho of layer-2 computes out-feature f(rho),
// chosen so the layer-2 C-layout IS the layer-3 B-frag layout (f(rho(kappa)))
// == kappa, so W3 staging stays in original order).
__device__ __forceinline__ int fperm(int n) {
  return ((n >> 5) << 5) + ((n >> 2) & 3) * 8 + ((n >> 4) & 1) * 4 + (n & 3);
}

__device__ __forceinline__ unsigned short f2bf(float f) {
  union { float f; unsigned u; } v; v.f = f;
  unsigned r = v.u + 0x7FFFu + ((v.u >> 16) & 1u);  // RNE
  return (unsigned short)(r >> 16);
}
__device__ __forceinline__ unsigned pk2bf(float a, float b) {
  __hip_bfloat162 h = __float22bfloat162_rn(float2{a, b});   // .x low16, .y high16
  union { __hip_bfloat162 h; unsigned u; } v; v.h = h;
  return v.u;
}
__device__ __forceinline__ f32x2 unpk_bf2(unsigned u) {
  union { unsigned u; float f; } lo, hi;
  lo.u = u << 16; hi.u = u & 0xffff0000u;
  return (f32x2){lo.f, hi.f};
}

// Wave-local LDS ordering fence (DS pipe is in-order per wave). Proven R3/R4.
__device__ __forceinline__ void wavefence() {
  __builtin_amdgcn_sched_barrier(0);
  __builtin_amdgcn_wave_barrier();
  __builtin_amdgcn_sched_barrier(0);
}

extern "C" __global__ void __launch_bounds__(NTHREADS, 2)
gnn_all(const float* __restrict__ pos, const int* __restrict__ z,
        const int* __restrict__ batch, const float* __restrict__ emb,
        const float* __restrict__ W1, const float* __restrict__ b1,
        const float* __restrict__ W2, const float* __restrict__ b2,
        const float* __restrict__ W3, const float* __restrict__ b3,
        float* __restrict__ out)
{
  extern __shared__ char lds[];
  unsigned short* w2t = (unsigned short*)(lds + OFF_W2);
  unsigned short* w3t = (unsigned short*)(lds + OFF_W3);
  float* bias2 = (float*)(lds + OFF_B2);
  unsigned short* Tl = (unsigned short*)(lds + OFF_T);
  float* embs = (float*)(lds + OFF_SCR);            // init-phase only
  float* slotsum = (float*)(lds + OFF_SLOT);
  int* slotcnt = (int*)(lds + OFF_CNT);

  const int t = threadIdx.x, b = blockIdx.x;
  const int wave = t >> 6, lane = t & 63, quad = lane >> 4, l15 = lane & 15;

  // ---- block's contiguous tile range: 61 tiles (+1 for first 9 blocks) ----
  const int tlo = 61 * b + (b < 9 ? b : 9);
  const int ntl = 61 + (b < 9 ? 1 : 0);
  const int start_node = tlo * WTILE;
  const int end_node = start_node + ntl * WTILE;    // <= N_NODES (15625 tiles exact)

  // ---- stage weights; W2 columns permuted by fperm (see above) ----
  for (int i = t; i < HID * HID; i += NTHREADS) {
    int k = i >> 7, n = i & 127;
    w2t[n * WPAD + k] = f2bf(W2[k * HID + fperm(n)]);
  }
  for (int i = t; i < HID * OUTD; i += NTHREADS) {  // W3^T original order
    int k = i >> 6, n = i & 63;
    w3t[n * WPAD + k] = f2bf(W3[i]);
  }
  // emb as f32 into scratch: [g][k], k zero-padded 125..131 (coalesced reads)
  for (int i = t; i < N_TYPES * EPAD; i += NTHREADS) {
    int g = i / EPAD, k = i - g * EPAD;
    embs[i] = (k < N_FEAT) ? emb[g * N_FEAT + k] : 0.f;
  }
  if (t < HID) bias2[t] = b2[fperm(t)];

  // ---- zero pooling slots ----
  for (int i = t; i < NSLOTS * OUTD; i += NTHREADS) slotsum[i] = 0.f;
  if (t < NSLOTS) slotcnt[t] = 0;

  // ---- ownership scalars (uniform across block) ----
  const int slot_base = batch[start_node];
  const int prev_g = (b == 0) ? -1 : batch[start_node - 1];
  const int own_hi = batch[end_node - 1];
  int n_ext = 0;
  if (end_node < N_NODES) {
    int probe = -1;
    if (lane < 12 && end_node + lane * WTILE < N_NODES)
      probe = batch[end_node + lane * WTILE];
    unsigned long long m = __ballot(probe == own_hi);
    n_ext = (int)__builtin_ctzll(~m);
    if (n_ext == 12) {
      while (end_node + WTILE * n_ext < N_NODES &&
             batch[end_node + WTILE * n_ext] == own_hi) ++n_ext;
    }
  }

  // ---- per-lane W1 pos-row coefficients as f32x2 pairs + b3 lane value ----
  f32x2 w1r2[3][4][4];
  #pragma unroll
  for (int c = 0; c < 3; ++c)
    #pragma unroll
    for (int k = 0; k < 4; ++k)
      #pragma unroll
      for (int p = 0; p < 4; ++p)
        w1r2[c][k][p] = *(const f32x2*)&W1[c * HID + k * 32 + quad * 8 + 2 * p];
  const float b3l = b3[lane];

  // ---- T-compute A-frags: W1[3:]^T bf16 straight from global (once) ----
  s16x8 afr[4];
  {
    const int jt = wave;
    #pragma unroll
    for (int kf = 0; kf < 4; ++kf) {
      s16x8 fr;
      #pragma unroll
      for (int u = 0; u < 8; ++u) {
        const int k = kf * 32 + quad * 8 + u;
        float v = (k < N_FEAT) ? W1[(3 + k) * HID + jt * 16 + l15] : 0.f;
        fr[u] = (short)f2bf(v);
      }
      afr[kf] = fr;
    }
  }

  __syncthreads();   // embs/w2t/w3t staged

  // ======== T = emb @ W1[3:] + b1 via MFMA (wave jt = wave's j-tile) ========
  {
    const int jt = wave;
    const int j0 = jt * 16 + quad * 4;
    const f32x4 b1v = *(const f32x4*)&b1[j0];

    for (int gt = 0; gt < 7; ++gt) {
      const int g = gt * 16 + l15;
      const int gg = (g < N_TYPES) ? g : (N_TYPES - 1);
      const float* erow = embs + gg * EPAD;
      f32x4 acc = {};
      #pragma unroll
      for (int kf = 0; kf < 4; ++kf) {
        const int k0 = kf * 32 + quad * 8;
        f32x4 e0 = *(const f32x4*)(erow + k0);
        f32x4 e1 = *(const f32x4*)(erow + k0 + 4);
        s16x8 bf;
        ((unsigned*)&bf)[0] = pk2bf(e0[0], e0[1]);
        ((unsigned*)&bf)[1] = pk2bf(e0[2], e0[3]);
        ((unsigned*)&bf)[2] = pk2bf(e1[0], e1[1]);
        ((unsigned*)&bf)[3] = pk2bf(e1[2], e1[3]);
        acc = __builtin_amdgcn_mfma_f32_16x16x32_bf16(afr[kf], bf, acc, 0, 0, 0);
      }
      if (g < N_TYPES) {
        unsigned lo = pk2bf(acc[0] + b1v[0], acc[1] + b1v[1]);
        unsigned hi = pk2bf(acc[2] + b1v[2], acc[3] + b1v[3]);
        *(uint2*)(Tl + g * WPAD + j0) = uint2{lo, hi};
      }
    }
  }

  float* xo = (float*)(lds + OFF_SCR + wave * SCR_BYTES);   // per-wave pool buf
  int* ids = (int*)(lds + OFF_IDS) + wave * WTILE;

  __syncthreads();   // Tl complete; embs region now free -> per-wave scratch

  // ---- W3 A-frags hoisted to registers (loop-invariant, 64 VGPR) ----
  s16x8 w3f[4][4];
  #pragma unroll
  for (int oi = 0; oi < 4; ++oi)
    #pragma unroll
    for (int kf = 0; kf < 4; ++kf)
      w3f[oi][kf] = *(const s16x8*)(w3t + (oi * 16 + l15) * WPAD + kf * 32 + quad * 8);

  // ================= main loop: waves stride the block's tiles =============
  const int ntot = ntl + n_ext;
  for (int j = wave; j < ntot; j += NWAVES) {
    const int base = start_node + j * WTILE;

    if (lane < WTILE) ids[lane] = batch[base + lane];

    // layer 1 in packed VALU, directly into MFMA B-fragments (x^T operand)
    s16x8 a[2][4];
    #pragma unroll
    for (int m = 0; m < 2; ++m) {
      const int node = base + m * 16 + l15;
      const int zi = z[node];
      const f32x2 px2 = {pos[node * 3], pos[node * 3]};
      const f32x2 py2 = {pos[node * 3 + 1], pos[node * 3 + 1]};
      const f32x2 pz2 = {pos[node * 3 + 2], pos[node * 3 + 2]};
      const unsigned short* Tr = Tl + zi * WPAD;
      #pragma unroll
      for (int k = 0; k < 4; ++k) {
        s16x8 tf = *(const s16x8*)(Tr + k * 32 + quad * 8);
        s16x8 fr;
        #pragma unroll
        for (int p = 0; p < 4; ++p) {
          f32x2 tv = unpk_bf2(((const unsigned*)&tf)[p]);
          tv = __builtin_elementwise_fma(px2, w1r2[0][k][p], tv);
          tv = __builtin_elementwise_fma(py2, w1r2[1][k][p], tv);
          tv = __builtin_elementwise_fma(pz2, w1r2[2][k][p], tv);
          tv = __builtin_elementwise_max(tv, (f32x2){0.f, 0.f});
          ((unsigned*)&fr)[p] = pk2bf(tv[0], tv[1]);
        }
        a[m][k] = fr;
      }
    }

    // layer 2 (fperm'd rows) + in-register repack into layer-3 B-frags.
    // oi-pair passes cap register pressure; C-layout == B-frag layout by fperm.
    s16x8 a3[2][4];
    #pragma unroll
    for (int p = 0; p < 4; ++p) {
      f32x4 acc2[2][2] = {};
      #pragma unroll
      for (int kf = 0; kf < 4; ++kf) {
        s16x8 w0 = *(const s16x8*)(w2t + ((2 * p) * 16 + l15) * WPAD + kf * 32 + quad * 8);
        s16x8 w1f = *(const s16x8*)(w2t + ((2 * p + 1) * 16 + l15) * WPAD + kf * 32 + quad * 8);
        acc2[0][0] = __builtin_amdgcn_mfma_f32_16x16x32_bf16(w0, a[0][kf], acc2[0][0], 0, 0, 0);
        acc2[0][1] = __builtin_amdgcn_mfma_f32_16x16x32_bf16(w0, a[1][kf], acc2[0][1], 0, 0, 0);
        acc2[1][0] = __builtin_amdgcn_mfma_f32_16x16x32_bf16(w1f, a[0][kf], acc2[1][0], 0, 0, 0);
        acc2[1][1] = __builtin_amdgcn_mfma_f32_16x16x32_bf16(w1f, a[1][kf], acc2[1][1], 0, 0, 0);
      }
      const f32x4 bv0 = *(const f32x4*)(bias2 + (2 * p) * 16 + quad * 4);
      const f32x4 bv1 = *(const f32x4*)(bias2 + (2 * p + 1) * 16 + quad * 4);
      #pragma unroll
      for (int m = 0; m < 2; ++m) {
        f32x4 s0 = __builtin_elementwise_max(acc2[0][m] + bv0, (f32x4){0.f, 0.f, 0.f, 0.f});
        f32x4 s1 = __builtin_elementwise_max(acc2[1][m] + bv1, (f32x4){0.f, 0.f, 0.f, 0.f});
        s16x8 fr;
        ((unsigned*)&fr)[0] = pk2bf(s0[0], s0[1]);
        ((unsigned*)&fr)[1] = pk2bf(s0[2], s0[3]);
        ((unsigned*)&fr)[2] = pk2bf(s1[0], s1[1]);
        ((unsigned*)&fr)[3] = pk2bf(s1[2], s1[3]);
        a3[m][p] = fr;
      }
    }

    // layer 3: register-resident W3 frags; no LDS round-trip before this
    f32x4 acc3[4][2] = {};
    #pragma unroll
    for (int oi = 0; oi < 4; ++oi)
      #pragma unroll
      for (int kf = 0; kf < 4; ++kf) {
        acc3[oi][0] = __builtin_amdgcn_mfma_f32_16x16x32_bf16(w3f[oi][kf], a3[0][kf], acc3[oi][0], 0, 0, 0);
        acc3[oi][1] = __builtin_amdgcn_mfma_f32_16x16x32_bf16(w3f[oi][kf], a3[1][kf], acc3[oi][1], 0, 0, 0);
      }
    #pragma unroll
    for (int oi = 0; oi < 4; ++oi)
      #pragma unroll
      for (int m = 0; m < 2; ++m)
        *(f32x4*)(xo + (m * 16 + l15) * OPADF + oi * 16 + quad * 4) = acc3[oi][m];
    wavefence();

    // pool into block-local LDS slots; mask runs not owned by this block
    {
      int cur = ids[0];
      float run = 0.f; int rc = 0;
      #pragma unroll 1
      for (int n = 0; n < WTILE; ++n) {
        int bb2 = ids[n];
        if (bb2 != cur) {
          if (cur != prev_g && cur <= own_hi) {
            atomicAdd(&slotsum[(cur - slot_base) * OUTD + lane], run);
            if (lane == 0) atomicAdd(&slotcnt[cur - slot_base], rc);
          }
          run = 0.f; rc = 0; cur = bb2;
        }
        run += xo[n * OPADF + lane]; rc++;
      }
      if (cur != prev_g && cur <= own_hi) {
        atomicAdd(&slotsum[(cur - slot_base) * OUTD + lane], run);
        if (lane == 0) atomicAdd(&slotcnt[cur - slot_base], rc);
      }
    }
    wavefence();   // next tile reuses xo/ids (same wave)
  }

  __syncthreads();   // all waves' slot contributions visible block-wide

  // ================= final writes: owned graphs + id-gap zero-fill =========
  const int own_lo = slot_base + (slot_base == prev_g ? 1 : 0);
  for (int g = own_lo + wave; g <= own_hi; g += NWAVES) {
    int s = g - slot_base;
    float sum = slotsum[s * OUTD + lane];
    int c = slotcnt[s];
    out[g * OUTD + lane] = (c > 0) ? (sum / (float)c + b3l) : 0.f;
  }
  const int next_g = (end_node < N_NODES) ? batch[end_node] : N_GRAPHS;
  for (int g = own_hi + 1 + wave; g < next_g; g += NWAVES)
    out[g * OUTD + lane] = 0.f;
  if (b == 0)
    for (int g = wave; g < slot_base; g += NWAVES)
      out[g * OUTD + lane] = 0.f;
}

extern "C" void kernel_launch(void* const* d_in, const int* in_sizes, int n_in,
                              void* d_out, int out_size, void* d_ws, size_t ws_size,
                              hipStream_t stream) {
  const float* pos  = (const float*)d_in[0];
  const int*   z    = (const int*)d_in[1];
  const int*   batch= (const int*)d_in[2];
  const float* emb  = (const float*)d_in[3];
  const float* W1   = (const float*)d_in[4];
  const float* b1   = (const float*)d_in[5];
  const float* W2   = (const float*)d_in[6];
  const float* b2   = (const float*)d_in[7];
  const float* W3   = (const float*)d_in[8];
  const float* b3   = (const float*)d_in[9];

  hipFuncSetAttribute((const void*)gnn_all,
                      hipFuncAttributeMaxDynamicSharedMemorySize, LDS_BYTES);

  hipLaunchKernelGGL(gnn_all, dim3(NBLOCKS), dim3(NTHREADS), LDS_BYTES, stream,
                     pos, z, batch, emb, W1, b1, W2, b2, W3, b3, (float*)d_out);
}